// Round 5
// baseline (120636.414 us; speedup 1.0000x reference)
//
#include <hip/hip_runtime.h>
#include <cstdint>
#include <cstddef>

// ---------------------------------------------------------------------------
// Seq2SeqNet: bidir GRU encoder (1024 steps) + attention GRU greedy decoder
// (256 steps). ALL math fp32, arithmetic order identical to the verified
// multi-launch kernel (greedy argmax feedback: ANY reassociation can flip a
// token). Architecture: the recurrence is PER-BATCH-ELEMENT independent, so
// NO grid-wide sync is needed at all. One persistent 1024-thread block per b
// runs all 256 decoder steps (intermediates in LDS, __syncthreads only);
// one 256-thread block per (b,dir) runs all 1024 encoder steps. No
// cooperative launches (round-2/4 measured grid.sync ~10-25us@128 blocks,
// ~95us@512 — fatal either way). Reductions keep exact tree shapes; element-
// parallel maps (GEMV rows, out0/out1 writes) are remapped freely (FP-safe);
// argmax is a (max,min-idx) semilattice (order-independent).
// ---------------------------------------------------------------------------

constexpr int kH = 512, kH2 = 256, kVC = 2000, kB = 64, kLIN = 1024, kT = 256;
constexpr int kSTART = 1;

// -------------------------------------------------------------------- zero
__global__ __launch_bounds__(256) void k_zero(float* p, int n) {
  int i = blockIdx.x * 256 + threadIdx.x;
  if (i < n) p[i] = 0.f;
}

// ------------------------------------------- encoder input-gate token table
__global__ __launch_bounds__(256)
void k_gi_table(const float* emb_jamo, const float* Wf, const float* Wb,
                const float* bihf, const float* bihb, float* gi) {
  int v = blockIdx.x >> 1, d = blockIdx.x & 1;
  const float* W = d ? Wb : Wf;
  const float* bih = d ? bihb : bihf;
  __shared__ float x[kH];
  for (int k = threadIdx.x; k < kH; k += 256) x[k] = emb_jamo[v * kH + k];
  __syncthreads();
  for (int j = threadIdx.x; j < 3 * kH2; j += 256) {
    float acc = bih[j];
    const float* row = W + (size_t)j * kH;
    for (int k = 0; k < kH; k += 4) {
      float4 f = *(const float4*)(row + k);
      acc += x[k] * f.x + x[k + 1] * f.y + x[k + 2] * f.z + x[k + 3] * f.w;
    }
    gi[(size_t)(v * 2 + d) * 768 + j] = acc;
  }
}

// ------------------ decoder embedding tables (bias folded)
__global__ __launch_bounds__(256)
void k_ac_emb(const float* emb_char, const float* attn_W, const float* attn_b,
              const float* comb_W, const float* comb_b, float* A, float* C) {
  int v = blockIdx.x;
  __shared__ float x[kH];
  for (int k = threadIdx.x; k < kH; k += 256) x[k] = emb_char[v * kH + k];
  __syncthreads();
  for (int j = threadIdx.x; j < kH; j += 256) {
    float a = attn_b[j], c = comb_b[j];
    const float* ra = attn_W + (size_t)j * 1024;
    const float* rc = comb_W + (size_t)j * 1024;
    for (int k = 0; k < kH; k += 4) {
      float4 fa = *(const float4*)(ra + k), fc = *(const float4*)(rc + k);
      a += x[k] * fa.x + x[k + 1] * fa.y + x[k + 2] * fa.z + x[k + 3] * fa.w;
      c += x[k] * fc.x + x[k + 1] * fc.y + x[k + 2] * fc.z + x[k + 3] * fc.w;
    }
    A[(size_t)v * kH + j] = a;
    C[(size_t)v * kH + j] = c;
  }
}

// ================= persistent per-(b,dir) encoder: no grid sync ============
// Thread u owns hidden unit u; h vector lives in LDS; dot order identical to
// the verified k_enc_step (hin[k*BC+b] == hsh[k] values).
__global__ __launch_bounds__(256)
void k_enc_pb(const int* tokens, const float* Whf, const float* Whb,
              const float* bhhf, const float* bhhb, const float* gi,
              float* enc, int b0) {
  int b = blockIdx.x >> 1, d = blockIdx.x & 1;
  int u = threadIdx.x;
  const float* Whh = d ? Whb : Whf;
  const float* bhh = d ? bhhb : bhhf;
  __shared__ float hsh[kH2];
  hsh[u] = 0.f;
  __syncthreads();
  const float* wr = Whh + (size_t)(0 * kH2 + u) * kH2;
  const float* wz = Whh + (size_t)(1 * kH2 + u) * kH2;
  const float* wn = Whh + (size_t)(2 * kH2 + u) * kH2;
  float br = bhh[u], bz = bhh[kH2 + u], bn = bhh[2 * kH2 + u];
  const int* myTok = tokens + (size_t)(b0 + b) * kLIN;
  float* encCol = enc + (size_t)b * kLIN * kH + d * kH2 + u;
  for (int t = 0; t < kLIN; ++t) {
    float ar = br, az = bz, an = bn;
    for (int k = 0; k < kH2; k += 4) {
      float4 fr = *(const float4*)(wr + k);
      float4 fz = *(const float4*)(wz + k);
      float4 fn = *(const float4*)(wn + k);
      float h0v = hsh[k], h1v = hsh[k + 1], h2v = hsh[k + 2], h3v = hsh[k + 3];
      ar += h0v * fr.x + h1v * fr.y + h2v * fr.z + h3v * fr.w;
      az += h0v * fz.x + h1v * fz.y + h2v * fz.z + h3v * fz.w;
      an += h0v * fn.x + h1v * fn.y + h2v * fn.z + h3v * fn.w;
    }
    int v = myTok[t];
    const float* git = gi + (size_t)(v * 2 + d) * 768;
    float r = 1.f / (1.f + expf(-(git[u] + ar)));
    float z = 1.f / (1.f + expf(-(git[kH2 + u] + az)));
    float n = tanhf(git[2 * kH2 + u] + r * an);
    float hprev = hsh[u];
    float hnew = (1.f - z) * n + z * hprev;
    __syncthreads();               // all dot-reads of hsh done
    hsh[u] = hnew;
    encCol[(size_t)t * kH] = hnew;
    __syncthreads();               // hsh update visible before next step
  }
}

// ================= persistent per-b decoder: no grid sync ==================
// 1024 threads = 4 subgroups of 256. Reduction trees per subgroup are
// bit-identical to the verified 256-thread phase bodies.
__global__ __launch_bounds__(1024, 1)
void k_dec_pb(const float* encAll, const float* cW, const float* Ctab,
              const float* dWi, const float* dWh, const float* dbi, const float* dbh,
              const float* oW, const float* ob, const float* aW, const float* Atab,
              const int* targets, const float* maskp,
              float* loss, float* out0, float* out1, int b0) {
  int b = blockIdx.x;
  int tid = threadIdx.x;
  int sg = tid >> 8, stid = tid & 255;
  int lane = stid & 63, w = stid >> 6, hl = lane & 31, half = lane >> 5;

  __shared__ float s_tile[4][128], e_tile[4][128], red[4][128];
  __shared__ float pm_s[8], pd_s[8];
  __shared__ float pctx_s[8][kH];
  __shared__ __align__(16) float sc_all[kLIN];
  __shared__ __align__(16) float key_s[kH];
  __shared__ __align__(16) float hbuf[2][kH];
  __shared__ __align__(16) float ctxl[kH];
  __shared__ __align__(16) float gt_s[kH];
  __shared__ float lg_s[kVC];
  __shared__ float rv[256]; __shared__ int ri[256]; __shared__ float rs[256];
  __shared__ float MD[2]; __shared__ float f8[8];
  __shared__ int tok_s;

  const float* encB = encAll + (size_t)b * kLIN * kH;
  int gb = b0 + b;

  // ---- prologue (verbatim k_prologue math): h0 = enc[b][1023], key ----
  for (int k = tid; k < kH; k += 1024) hbuf[0][k] = encB[(size_t)(kLIN - 1) * kH + k];
  if (tid == 0) tok_s = kSTART;
  __syncthreads();
  if (tid < kH) {
    int j = tid;
    const float* row = aW + (size_t)j * 1024 + 512;
    float acc = Atab[(size_t)kSTART * kH + j];
    for (int k = 0; k < kH; k += 4) {
      float4 f = *(const float4*)(row + k);
      acc += hbuf[0][k] * f.x + hbuf[0][k + 1] * f.y + hbuf[0][k + 2] * f.z + hbuf[0][k + 3] * f.w;
    }
    key_s[j] = acc;
  }
  __syncthreads();

  for (int t = 0; t < kT; ++t) {
    int pp = t & 1;
    const float* hprev = hbuf[pp];
    float* hnew = hbuf[1 - pp];

    // ---------------- phase A: 8 l-tiles, 2 rounds x 4 subgroups ----------
    float kreg[16];
#pragma unroll
    for (int m = 0; m < 16; m += 4) *(float4*)(kreg + m) = *(const float4*)(key_s + hl * 16 + m);
    for (int r = 0; r < 2; ++r) {
      int lt = sg + r * 4;
      for (int i0 = 0; i0 < 16; i0 += 2) {   // score pass, 2-row ILP batches
        float4 v[2][4];
#pragma unroll
        for (int j = 0; j < 2; j++) {
          int ll = w * 32 + (i0 + j) * 2 + half;
          const float* row = encB + (size_t)(lt * 128 + ll) * kH + hl * 16;
#pragma unroll
          for (int m = 0; m < 4; m++) v[j][m] = *(const float4*)(row + m * 4);
        }
#pragma unroll
        for (int j = 0; j < 2; j++) {
          int ll = w * 32 + (i0 + j) * 2 + half;
          float acc = 0.f;
#pragma unroll
          for (int m = 0; m < 4; m++)
            acc += v[j][m].x * kreg[4 * m] + v[j][m].y * kreg[4 * m + 1] +
                   v[j][m].z * kreg[4 * m + 2] + v[j][m].w * kreg[4 * m + 3];
#pragma unroll
          for (int m2 = 16; m2 > 0; m2 >>= 1) acc += __shfl_xor(acc, m2, 32);
          if (hl == 0) { s_tile[sg][ll] = acc; sc_all[lt * 128 + ll] = acc; }
        }
      }
      __syncthreads();
      if (stid < 128) red[sg][stid] = s_tile[sg][stid];
      __syncthreads();
      for (int s = 64; s > 0; s >>= 1) {
        if (stid < s) red[sg][stid] = fmaxf(red[sg][stid], red[sg][stid + s]);
        __syncthreads();
      }
      float mt = red[sg][0];
      __syncthreads();
      if (stid < 128) { e_tile[sg][stid] = expf(s_tile[sg][stid] - mt); red[sg][stid] = e_tile[sg][stid]; }
      __syncthreads();
      for (int s = 64; s > 0; s >>= 1) {
        if (stid < s) red[sg][stid] += red[sg][stid + s];
        __syncthreads();
      }
      float dt = red[sg][0];
      int h0i = stid * 2;
      float cx = 0.f, cy = 0.f;
      const float* base = encB + (size_t)(lt * 128) * kH + h0i;
      for (int l0 = 0; l0 < 128; l0 += 4) {   // ctx pass, order unchanged
        float2 v0 = *(const float2*)(base + (size_t)(l0 + 0) * kH);
        float2 v1 = *(const float2*)(base + (size_t)(l0 + 1) * kH);
        float2 v2 = *(const float2*)(base + (size_t)(l0 + 2) * kH);
        float2 v3 = *(const float2*)(base + (size_t)(l0 + 3) * kH);
        float e0 = e_tile[sg][l0], e1 = e_tile[sg][l0 + 1];
        float e2 = e_tile[sg][l0 + 2], e3 = e_tile[sg][l0 + 3];
        cx += e0 * v0.x; cy += e0 * v0.y;
        cx += e1 * v1.x; cy += e1 * v1.y;
        cx += e2 * v2.x; cy += e2 * v2.y;
        cx += e3 * v3.x; cy += e3 * v3.y;
      }
      pctx_s[lt][h0i] = cx; pctx_s[lt][h0i + 1] = cy;
      if (stid == 0) { pm_s[lt] = mt; pd_s[lt] = dt; }
      __syncthreads();
    }

    // ---------------- phase B: combine -> ctx, out1, gt -------------------
    if (tid == 0) {
      float M = -1e30f;
      for (int i = 0; i < 8; i++) M = fmaxf(M, pm_s[i]);
      float D = 0.f;
      for (int i = 0; i < 8; i++) {
        float f = expf(pm_s[i] - M);
        f8[i] = f; D += f * pd_s[i];
      }
      MD[0] = M; MD[1] = 1.f / D;
    }
    __syncthreads();
    float M = MD[0], invD = MD[1];
    if (tid < 256) {
      int h0i = tid * 2;
      float cx = 0.f, cy = 0.f;
      for (int i = 0; i < 8; i++) { cx += f8[i] * pctx_s[i][h0i]; cy += f8[i] * pctx_s[i][h0i + 1]; }
      ctxl[h0i] = cx * invD; ctxl[h0i + 1] = cy * invD;
    }
    out1[((size_t)gb * kLIN + tid) * kT + t] = expf(sc_all[tid] - M) * invD;  // 1024 l
    __syncthreads();
    if (tid < kH) {
      int j = tid, tk = tok_s;
      const float* row = cW + (size_t)j * 1024 + 512;
      float acc = Ctab[(size_t)tk * kH + j];
      for (int k = 0; k < kH; k += 4) {
        float4 f = *(const float4*)(row + k);
        acc += ctxl[k] * f.x + ctxl[k + 1] * f.y + ctxl[k + 2] * f.z + ctxl[k + 3] * f.w;
      }
      gt_s[j] = fmaxf(acc, 0.f);
    }
    __syncthreads();

    // ---------------- phase C: GRU, thread per u --------------------------
    if (tid < kH) {
      int u = tid;
      float air = dbi[u], aiz = dbi[kH + u], ain = dbi[2 * kH + u];
      float ahr = dbh[u], ahz = dbh[kH + u], ahn = dbh[2 * kH + u];
      const float* wir = dWi + (size_t)(0 * kH + u) * kH;
      const float* wiz = dWi + (size_t)(1 * kH + u) * kH;
      const float* win = dWi + (size_t)(2 * kH + u) * kH;
      const float* whr = dWh + (size_t)(0 * kH + u) * kH;
      const float* whz = dWh + (size_t)(1 * kH + u) * kH;
      const float* whn = dWh + (size_t)(2 * kH + u) * kH;
      for (int k = 0; k < kH; k += 4) {
        float4 fir = *(const float4*)(wir + k), fiz = *(const float4*)(wiz + k), fin = *(const float4*)(win + k);
        float4 fhr = *(const float4*)(whr + k), fhz = *(const float4*)(whz + k), fhn = *(const float4*)(whn + k);
        float g0 = gt_s[k], g1 = gt_s[k + 1], g2 = gt_s[k + 2], g3 = gt_s[k + 3];
        float h0v = hprev[k], h1v = hprev[k + 1], h2v = hprev[k + 2], h3v = hprev[k + 3];
        air += g0 * fir.x + g1 * fir.y + g2 * fir.z + g3 * fir.w;
        aiz += g0 * fiz.x + g1 * fiz.y + g2 * fiz.z + g3 * fiz.w;
        ain += g0 * fin.x + g1 * fin.y + g2 * fin.z + g3 * fin.w;
        ahr += h0v * fhr.x + h1v * fhr.y + h2v * fhr.z + h3v * fhr.w;
        ahz += h0v * fhz.x + h1v * fhz.y + h2v * fhz.z + h3v * fhz.w;
        ahn += h0v * fhn.x + h1v * fhn.y + h2v * fhn.z + h3v * fhn.w;
      }
      float rr = 1.f / (1.f + expf(-(air + ahr)));
      float zz = 1.f / (1.f + expf(-(aiz + ahz)));
      float nn = tanhf(ain + rr * ahn);
      float hp = hprev[u];
      hnew[u] = (1.f - zz) * nn + zz * hp;
    }
    __syncthreads();

    // ---------------- phase D: logits, 8 c-tiles, 2 rounds x 4 sg ---------
    {
      float hreg[16];
#pragma unroll
      for (int m = 0; m < 16; m += 4) *(float4*)(hreg + m) = *(const float4*)(&hnew[hl * 16 + m]);
      for (int r = 0; r < 2; ++r) {
        int ct = sg + r * 4;
        int c0 = ct * 250;
        for (int i0 = 0; i0 < 32; i0 += 2) {
          int ca = c0 + (i0 + 0) * 8 + w * 2 + half;
          int cb = c0 + (i0 + 1) * 8 + w * 2 + half;
          int cca = ca < kVC ? ca : kVC - 1;
          int ccb = cb < kVC ? cb : kVC - 1;
          float4 va[4], vb[4];
          const float* rowa = oW + (size_t)cca * kH + hl * 16;
          const float* rowb = oW + (size_t)ccb * kH + hl * 16;
#pragma unroll
          for (int m = 0; m < 4; m++) { va[m] = *(const float4*)(rowa + m * 4); vb[m] = *(const float4*)(rowb + m * 4); }
          float acca = 0.f, accb = 0.f;
#pragma unroll
          for (int m = 0; m < 4; m++)
            acca += va[m].x * hreg[4 * m] + va[m].y * hreg[4 * m + 1] +
                    va[m].z * hreg[4 * m + 2] + va[m].w * hreg[4 * m + 3];
#pragma unroll
          for (int m = 0; m < 4; m++)
            accb += vb[m].x * hreg[4 * m] + vb[m].y * hreg[4 * m + 1] +
                    vb[m].z * hreg[4 * m + 2] + vb[m].w * hreg[4 * m + 3];
#pragma unroll
          for (int m2 = 16; m2 > 0; m2 >>= 1) acca += __shfl_xor(acca, m2, 32);
#pragma unroll
          for (int m2 = 16; m2 > 0; m2 >>= 1) accb += __shfl_xor(accb, m2, 32);
          if (ca < c0 + 250 && hl == 0) lg_s[ca] = acca + ob[ca];
          if (cb < c0 + 250 && hl == 0) lg_s[cb] = accb + ob[cb];
        }
      }
    }
    __syncthreads();

    // ---------------- phase E: argmax + lse (sg0, exact trees) ------------
    float xv[8];
    if (sg == 0) {
      float bv = -3.4e38f; int bi = kVC;
#pragma unroll
      for (int i = 0; i < 8; i++) {
        int c = stid + i * 256;
        float x = (c < kVC) ? lg_s[c] : -3.4e38f;
        xv[i] = x;
        if (x > bv) { bv = x; bi = c; }
      }
      rv[stid] = bv; ri[stid] = bi;
    }
    __syncthreads();
    for (int s = 128; s > 0; s >>= 1) {
      if (sg == 0 && stid < s) {
        float v2 = rv[stid + s]; int i2 = ri[stid + s];
        if (v2 > rv[stid] || (v2 == rv[stid] && i2 < ri[stid])) { rv[stid] = v2; ri[stid] = i2; }
      }
      __syncthreads();
    }
    float Me = rv[0]; int nt = ri[0];
    if (sg == 0) {
      float se = 0.f;
#pragma unroll
      for (int i = 0; i < 8; i++) { int c = stid + i * 256; if (c < kVC) se += expf(xv[i] - Me); }
      rs[stid] = se;
    }
    __syncthreads();
    for (int s = 128; s > 0; s >>= 1) {
      if (sg == 0 && stid < s) rs[stid] += rs[stid + s];
      __syncthreads();
    }
    float lse = Me + logf(rs[0]);
    for (int c = tid; c < kVC; c += 1024)
      out0[((size_t)gb * kT + t) * kVC + c] = lg_s[c] - lse;
    if (tid == 0) {
      tok_s = nt;
      int tg = targets[(size_t)gb * kT + t];
      float mk = maskp[(size_t)gb * kT + t];
      atomicAdd(loss, (lse - lg_s[tg]) * mk * (1.f / 16384.f));  // /B /T
    }
    if (tid < kH) {   // next-step key (verbatim order: A[nt] then k-dot)
      int j = tid;
      const float* row = aW + (size_t)j * 1024 + 512;
      float acc = Atab[(size_t)nt * kH + j];
      for (int k = 0; k < kH; k += 4) {
        float4 f = *(const float4*)(row + k);
        acc += hnew[k] * f.x + hnew[k + 1] * f.y + hnew[k + 2] * f.z + hnew[k + 3] * f.w;
      }
      key_s[j] = acc;
    }
    __syncthreads();
  }
}

__global__ void k_loss_out(float* dst, const float* loss) {
  if (threadIdx.x == 0 && blockIdx.x == 0) *dst = *loss;
}

// ---------------------------------------------------------------------------
extern "C" void kernel_launch(void* const* d_in, const int* in_sizes, int n_in,
                              void* d_out, int out_size, void* d_ws, size_t ws_size,
                              hipStream_t stream) {
  (void)in_sizes; (void)n_in;
  const int*   tok_in = (const int*)d_in[0];
  const int*   tgt    = (const int*)d_in[1];
  const float* mask   = (const float*)d_in[2];
  const float* emb_j  = (const float*)d_in[3];
  const float* emb_c  = (const float*)d_in[4];
  const float* eWif   = (const float*)d_in[5];
  const float* eWhf   = (const float*)d_in[6];
  const float* ebif   = (const float*)d_in[7];
  const float* ebhf   = (const float*)d_in[8];
  const float* eWib   = (const float*)d_in[9];
  const float* eWhb   = (const float*)d_in[10];
  const float* ebib   = (const float*)d_in[11];
  const float* ebhb   = (const float*)d_in[12];
  const float* dWi    = (const float*)d_in[13];
  const float* dWh    = (const float*)d_in[14];
  const float* dbi    = (const float*)d_in[15];
  const float* dbh    = (const float*)d_in[16];
  const float* aW     = (const float*)d_in[17];
  const float* ab     = (const float*)d_in[18];
  const float* cW     = (const float*)d_in[19];
  const float* cb     = (const float*)d_in[20];
  const float* oW     = (const float*)d_in[21];
  const float* ob     = (const float*)d_in[22];
  float* ws   = (float*)d_ws;
  float* out0 = (float*)d_out;
  float* out1 = out0 + (size_t)kB * kT * kVC;

  // ---- workspace layout (floats)
  const size_t GI   = 0;
  const size_t A    = GI + 107520;          // 70*2*768
  const size_t C    = A + 1024000;          // 2000*512
  const size_t LOSS = C + 1024000;
  const size_t ENC  = LOSS + 1;             // + BC*1024*512

  int BC = 64;
  while (BC > 8 && (ENC + (size_t)BC * kLIN * kH) * sizeof(float) > ws_size) BC >>= 1;
  int NC = kB / BC;

  float* gi_p   = ws + GI;
  float* A_p    = ws + A;
  float* C_p    = ws + C;
  float* loss_p = ws + LOSS;
  float* enc_p  = ws + ENC;

  k_zero<<<1, 256, 0, stream>>>(loss_p, 1);
  k_gi_table<<<140, 256, 0, stream>>>(emb_j, eWif, eWib, ebif, ebib, gi_p);
  k_ac_emb<<<2000, 256, 0, stream>>>(emb_c, aW, ab, cW, cb, A_p, C_p);

  for (int c = 0; c < NC; c++) {
    int b0 = c * BC;
    k_enc_pb<<<2 * BC, 256, 0, stream>>>(tok_in, eWhf, eWhb, ebhf, ebhb,
                                         gi_p, enc_p, b0);
    k_dec_pb<<<BC, 1024, 0, stream>>>(enc_p, cW, C_p, dWi, dWh, dbi, dbh,
                                      oW, ob, aW, A_p, tgt, mask,
                                      loss_p, out0, out1, b0);
  }
  k_loss_out<<<1, 64, 0, stream>>>(out0 + (size_t)out_size - 1, loss_p);
}